// Round 2
// baseline (474.796 us; speedup 1.0000x reference)
//
#include <hip/hip_runtime.h>
#include <cmath>

#define B_   4
#define H_   16
#define KVH_ 4
#define D_   256
#define HID_ 4096
#define PAST_ 8191
#define S_   8192
#define KKEEP_ 2048
#define R_   128

// workspace layout (float offsets) — total 2,664,448 floats (~10.66 MB),
// within the footprint of the previously-verified kernel.
#define OFF_Q     0         // 16384
#define OFF_KN    16384     // 4096
#define OFF_VN    20480     // 4096
#define OFF_SCALE 24576     // 64
#define OFF_CMASK 24640     // 512
#define OFF_ROPE  25152     // 1024
#define OFF_KBM   26176     // 16384 (dead after K3b; yflat aliases it)
#define OFF_CNT   42560     // 16
#define OFF_F     43008     // fsc 524288 (dead after K3; pc aliases it)
#define OFF_A     567296    // asc 524288 (dead after K3; list aliases first 131072)
#define OFF_P     1091584   // probs 524288
#define OFF_YP    1615872   // ypart 64*16*1024 = 1048576
// aliases:
#define OFF_PC    OFF_F     // 16*4*8192 = 524288 floats
#define OFF_LIST  OFF_A     // 16*8192 = 131072 ints
#define OFF_Y     OFF_KBM   // 16384 floats

// ---------------- K0: RoPE cos/sin table (bitwise-identical math to old per-block tail) ----------------
__global__ __launch_bounds__(256) void k0_rope(const int* __restrict__ pos_ids, float* __restrict__ ropet)
{
    for (int e = threadIdx.x; e < 512; e += 256) {
        int b = e >> 7, d = e & 127;
        float x = (float)d * (1.0f / 128.0f);
        float invf = 1.0f / powf(10000.0f, x);
        float ang = (float)pos_ids[b] * invf;
        double ad = (double)ang;
        ropet[e * 2]     = (float)cos(ad);
        ropet[e * 2 + 1] = (float)sin(ad);
    }
}

// ---------------- K1: QKV GEMV + RoPE ----------------
__global__ __launch_bounds__(256) void k1_qkv(
    const float* __restrict__ hidden, const float* __restrict__ ropet,
    const float* __restrict__ Wq, const float* __restrict__ Wk, const float* __restrict__ Wv,
    float* __restrict__ q_ws, float* __restrict__ knew, float* __restrict__ vnew)
{
    int slot = blockIdx.x >> 7;
    int d    = blockIdx.x & 127;
    const float* W; float* outp; int head; bool rope; int bstride;
    if (slot < 16)      { W = Wq; head = slot;      outp = q_ws + head * D_; rope = true;  bstride = H_ * D_; }
    else if (slot < 20) { W = Wk; head = slot - 16; outp = knew + head * D_; rope = true;  bstride = KVH_ * D_; }
    else                { W = Wv; head = slot - 20; outp = vnew + head * D_; rope = false; bstride = KVH_ * D_; }

    int rowbase = head * D_ + d;
    const float* w0 = W + (size_t)rowbase * HID_;
    const float* w1 = W + (size_t)(rowbase + 128) * HID_;

    float acc0[4] = {0.f, 0.f, 0.f, 0.f};
    float acc1[4] = {0.f, 0.f, 0.f, 0.f};
#pragma unroll
    for (int i = 0; i < 4; ++i) {
        int c = (threadIdx.x + 256 * i) * 4;
        float4 a0 = *(const float4*)(w0 + c);
        float4 a1 = *(const float4*)(w1 + c);
#pragma unroll
        for (int b = 0; b < 4; ++b) {
            float4 hv = *(const float4*)(hidden + b * HID_ + c);
            acc0[b] += a0.x * hv.x + a0.y * hv.y + a0.z * hv.z + a0.w * hv.w;
            acc1[b] += a1.x * hv.x + a1.y * hv.y + a1.z * hv.z + a1.w * hv.w;
        }
    }
#pragma unroll
    for (int off = 1; off < 64; off <<= 1) {
#pragma unroll
        for (int b = 0; b < 4; ++b) {
            acc0[b] += __shfl_xor(acc0[b], off, 64);
            acc1[b] += __shfl_xor(acc1[b], off, 64);
        }
    }
    __shared__ float red[4][8];
    int wv = threadIdx.x >> 6, ln = threadIdx.x & 63;
    if (ln == 0) {
#pragma unroll
        for (int b = 0; b < 4; ++b) { red[wv][b] = acc0[b]; red[wv][4 + b] = acc1[b]; }
    }
    __syncthreads();
    if (threadIdx.x == 0) {
        for (int b = 0; b < 4; ++b) {
            float s0 = red[0][b] + red[1][b] + red[2][b] + red[3][b];
            float s1 = red[0][4 + b] + red[1][4 + b] + red[2][4 + b] + red[3][4 + b];
            float o0, o1;
            if (rope) {
                float c  = ropet[(b * 128 + d) * 2];
                float sn = ropet[(b * 128 + d) * 2 + 1];
                o0 = s0 * c - s1 * sn;
                o1 = s1 * c + s0 * sn;
            } else { o0 = s0; o1 = s1; }
            outp[b * bstride + d]       = o0;
            outp[b * bstride + d + 128] = o1;
        }
    }
}

// ---------------- K1b: top-128 channel selection per (b,h) ----------------
__global__ __launch_bounds__(256) void k1b_chan(
    const float* __restrict__ q_ws, float* __restrict__ scale_ws, unsigned* __restrict__ cmask_ws)
{
    int bh = blockIdx.x;
    int t  = threadIdx.x;
    __shared__ unsigned ua[256];
    __shared__ float red[256];
    __shared__ unsigned bm[8];
    __shared__ float s_all;

    float qv = q_ws[bh * 256 + t];
    float aq = fabsf(qv);
    ua[t] = __float_as_uint(aq);
    if (t < 8) bm[t] = 0u;
    __syncthreads();

    unsigned mine = ua[t];
    int rank = 0;
    for (int i = 0; i < 256; ++i) {
        unsigned o = ua[i];
        rank += (o > mine) || (o == mine && i < t);
    }
    bool kept = rank < R_;
    if (kept) atomicOr(&bm[t >> 5], 1u << (t & 31));

    red[t] = aq; __syncthreads();
    for (int off = 128; off; off >>= 1) { if (t < off) red[t] += red[t + off]; __syncthreads(); }
    if (t == 0) s_all = red[0];
    __syncthreads();
    red[t] = kept ? aq : 0.f; __syncthreads();
    for (int off = 128; off; off >>= 1) { if (t < off) red[t] += red[t + off]; __syncthreads(); }
    if (t == 0) scale_ws[bh] = sqrtf(256.0f * red[0] / s_all);
    if (t < 8) cmask_ws[bh * 8 + t] = bm[t];
}

// ---------------- K2: full + approx scores (2-row deep prefetch) ----------------
__global__ __launch_bounds__(256) void k2_scores(
    const float* __restrict__ past_key, const float* __restrict__ knew,
    const float* __restrict__ q_ws, const float* __restrict__ scale_ws,
    const unsigned* __restrict__ cmask_ws, const float* __restrict__ amask,
    float* __restrict__ fsc, float* __restrict__ asc)
{
    int bkv   = blockIdx.x >> 7;
    int chunk = blockIdx.x & 127;
    int b = bkv >> 2, kvh = bkv & 3;
    int w = threadIdx.x >> 6, lane = threadIdx.x & 63;
    int g = lane >> 4, m = lane & 15;
    int h = kvh * 4 + g;

    const float* qp = q_ws + (b * H_ + h) * D_;
    const unsigned* cm = cmask_ws + (b * H_ + h) * 8;
    float inv_scale = 1.0f / scale_ws[b * H_ + h];

    float qr[16], ar[16];
#pragma unroll
    for (int i = 0; i < 4; ++i)
#pragma unroll
        for (int t = 0; t < 4; ++t) {
            int c = i * 64 + m * 4 + t;
            float q = qp[c];
            qr[i * 4 + t] = q;
            ar[i * 4 + t] = ((cm[c >> 5] >> (c & 31)) & 1u) ? q : 0.f;
        }

    const float* kbase = past_key + (size_t)(b * KVH_ + kvh) * PAST_ * D_;
    const float* knrow = knew + (b * KVH_ + kvh) * D_;
    float* fout = fsc + (size_t)(b * H_ + h) * S_;
    float* aout = asc + (size_t)(b * H_ + h) * S_;
    const float* mrow = amask + b * S_;
    int s0 = chunk * 64 + w * 16;

    const float* rA = (s0     < PAST_) ? (kbase + (size_t)s0 * D_)       : knrow;
    const float* rB = (s0 + 1 < PAST_) ? (kbase + (size_t)(s0 + 1) * D_) : knrow;
    float4 nA0 = *(const float4*)(rA + m * 4);
    float4 nA1 = *(const float4*)(rA + 64 + m * 4);
    float4 nA2 = *(const float4*)(rA + 128 + m * 4);
    float4 nA3 = *(const float4*)(rA + 192 + m * 4);
    float4 nB0 = *(const float4*)(rB + m * 4);
    float4 nB1 = *(const float4*)(rB + 64 + m * 4);
    float4 nB2 = *(const float4*)(rB + 128 + m * 4);
    float4 nB3 = *(const float4*)(rB + 192 + m * 4);

    for (int it = 0; it < 8; ++it) {
        int sA = s0 + 2 * it;
        float4 cA0 = nA0, cA1 = nA1, cA2 = nA2, cA3 = nA3;
        float4 cB0 = nB0, cB1 = nB1, cB2 = nB2, cB3 = nB3;
        if (it < 7) {
            int sn = sA + 2;
            const float* pA = (sn     < PAST_) ? (kbase + (size_t)sn * D_)       : knrow;
            const float* pB = (sn + 1 < PAST_) ? (kbase + (size_t)(sn + 1) * D_) : knrow;
            nA0 = *(const float4*)(pA + m * 4);
            nA1 = *(const float4*)(pA + 64 + m * 4);
            nA2 = *(const float4*)(pA + 128 + m * 4);
            nA3 = *(const float4*)(pA + 192 + m * 4);
            nB0 = *(const float4*)(pB + m * 4);
            nB1 = *(const float4*)(pB + 64 + m * 4);
            nB2 = *(const float4*)(pB + 128 + m * 4);
            nB3 = *(const float4*)(pB + 192 + m * 4);
        }
        float fullA = 0.f, apprA = 0.f, fullB = 0.f, apprB = 0.f;
        fullA += qr[0]*cA0.x + qr[1]*cA0.y + qr[2]*cA0.z + qr[3]*cA0.w;
        apprA += ar[0]*cA0.x + ar[1]*cA0.y + ar[2]*cA0.z + ar[3]*cA0.w;
        fullA += qr[4]*cA1.x + qr[5]*cA1.y + qr[6]*cA1.z + qr[7]*cA1.w;
        apprA += ar[4]*cA1.x + ar[5]*cA1.y + ar[6]*cA1.z + ar[7]*cA1.w;
        fullA += qr[8]*cA2.x + qr[9]*cA2.y + qr[10]*cA2.z + qr[11]*cA2.w;
        apprA += ar[8]*cA2.x + ar[9]*cA2.y + ar[10]*cA2.z + ar[11]*cA2.w;
        fullA += qr[12]*cA3.x + qr[13]*cA3.y + qr[14]*cA3.z + qr[15]*cA3.w;
        apprA += ar[12]*cA3.x + ar[13]*cA3.y + ar[14]*cA3.z + ar[15]*cA3.w;
        fullB += qr[0]*cB0.x + qr[1]*cB0.y + qr[2]*cB0.z + qr[3]*cB0.w;
        apprB += ar[0]*cB0.x + ar[1]*cB0.y + ar[2]*cB0.z + ar[3]*cB0.w;
        fullB += qr[4]*cB1.x + qr[5]*cB1.y + qr[6]*cB1.z + qr[7]*cB1.w;
        apprB += ar[4]*cB1.x + ar[5]*cB1.y + ar[6]*cB1.z + ar[7]*cB1.w;
        fullB += qr[8]*cB2.x + qr[9]*cB2.y + qr[10]*cB2.z + qr[11]*cB2.w;
        apprB += ar[8]*cB2.x + ar[9]*cB2.y + ar[10]*cB2.z + ar[11]*cB2.w;
        fullB += qr[12]*cB3.x + qr[13]*cB3.y + qr[14]*cB3.z + qr[15]*cB3.w;
        apprB += ar[12]*cB3.x + ar[13]*cB3.y + ar[14]*cB3.z + ar[15]*cB3.w;
#pragma unroll
        for (int off = 1; off < 16; off <<= 1) {
            fullA += __shfl_xor(fullA, off, 64);
            apprA += __shfl_xor(apprA, off, 64);
            fullB += __shfl_xor(fullB, off, 64);
            apprB += __shfl_xor(apprB, off, 64);
        }
        float2 mv = *(const float2*)(mrow + sA);
        if (m == 0) {
            float2 o; o.x = fullA * 0.0625f + mv.x; o.y = fullB * 0.0625f + mv.y;
            *(float2*)(fout + sA) = o;
        } else if (m == 1) {
            float2 o; o.x = apprA * inv_scale + mv.x; o.y = apprB * inv_scale + mv.y;
            *(float2*)(aout + sA) = o;
        }
    }
}

// ---------------- K3: radix-select top-2048 + softmax -> probs (+ keep bitmap) ----------------
#define PAD(s) ((s) + ((s) >> 5))
__global__ __launch_bounds__(1024) void k3_select(
    const float* __restrict__ fsc, const float* __restrict__ asc,
    float* __restrict__ probs, unsigned* __restrict__ kbm)
{
    int bh = blockIdx.x;
    int t  = threadIdx.x;
    int lane = t & 63, wid = t >> 6;
    __shared__ unsigned ua[8448];
    __shared__ unsigned hist2[16 * 257];
    __shared__ unsigned hist[256];
    __shared__ unsigned sf[256];
    __shared__ int wsum[16], wbase[16];
    __shared__ float wred[16];
    __shared__ unsigned sh_bin; __shared__ int sh_rem;
    __shared__ float sh_M, sh_Z;

    const float* ap = asc + (size_t)bh * S_;
    const float* fp = fsc + (size_t)bh * S_;

#pragma unroll
    for (int i = 0; i < 8; ++i) {
        int s = i * 1024 + t;
        unsigned u = __float_as_uint(ap[s]);
        u ^= (u & 0x80000000u) ? 0xFFFFFFFFu : 0x80000000u;
        ua[PAD(s)] = u;
    }

    unsigned prefix = 0; int rem = KKEEP_;
    for (int pass = 0; pass < 4; ++pass) {
        const int shift = 24 - 8 * pass;
        for (int j = t; j < 16 * 257; j += 1024) hist2[j] = 0;
        __syncthreads();
#pragma unroll
        for (int i = 0; i < 8; ++i) {
            unsigned u = ua[PAD(i * 1024 + t)];
            bool match = (pass == 0) || ((u >> (shift + 8)) == prefix);
            if (match) atomicAdd(&hist2[wid * 257 + ((u >> shift) & 255u)], 1u);
        }
        __syncthreads();
        if (t < 256) {
            unsigned hsum = 0;
#pragma unroll
            for (int w2 = 0; w2 < 16; ++w2) hsum += hist2[w2 * 257 + t];
            hist[t] = hsum;
        }
        __syncthreads();
        if (t < 64) {
            unsigned h0 = hist[t*4], h1 = hist[t*4+1], h2 = hist[t*4+2], h3 = hist[t*4+3];
            unsigned loc = h0 + h1 + h2 + h3;
            unsigned run = loc;
#pragma unroll
            for (int off = 1; off < 64; off <<= 1) {
                unsigned v = __shfl_down(run, off, 64);
                if (t + off < 64) run += v;
            }
            unsigned tail = run - loc;
            sf[t*4+3] = tail + h3;
            sf[t*4+2] = tail + h3 + h2;
            sf[t*4+1] = tail + h3 + h2 + h1;
            sf[t*4+0] = tail + loc;
        }
        __syncthreads();
        if (t < 256) {
            unsigned above = (t == 255) ? 0u : sf[t + 1];
            if (sf[t] >= (unsigned)rem && above < (unsigned)rem) {
                sh_bin = (unsigned)t;
                sh_rem = rem - (int)above;
            }
        }
        __syncthreads();
        prefix = (prefix << 8) | sh_bin;
        rem = sh_rem;
        __syncthreads();
    }
    unsigned ut = prefix; int Need = rem;

    int cnt = 0;
#pragma unroll
    for (int i = 0; i < 8; ++i)
        cnt += (ua[PAD(t * 8 + i)] == ut) ? 1 : 0;
    int inc = cnt;
#pragma unroll
    for (int off = 1; off < 64; off <<= 1) {
        int v = __shfl_up(inc, off, 64);
        if (lane >= off) inc += v;
    }
    if (lane == 63) wsum[wid] = inc;
    __syncthreads();
    if (t == 0) {
        int run = 0;
#pragma unroll
        for (int j = 0; j < 16; ++j) { int c = wsum[j]; wbase[j] = run; run += c; }
    }
    __syncthreads();
    int eqb = wbase[wid] + inc - cnt;
#pragma unroll
    for (int i = 0; i < 8; ++i) {
        int s = t * 8 + i;
        if (ua[PAD(s)] == ut) {
            ua[PAD(s)] = (eqb < Need) ? 0xFFFFFFFFu : 0u;
            ++eqb;
        }
    }
    __syncthreads();

    float m = -3.4e38f, z = 0.f;
#pragma unroll
    for (int i = 0; i < 8; ++i) {
        int s = i * 1024 + t;
        if (ua[PAD(s)] > ut) {
            float f = fp[s];
            if (f > m) { z = z * expf(m - f) + 1.f; m = f; }
            else       { z += expf(f - m); }
        }
    }
    float wm = m;
#pragma unroll
    for (int off = 1; off < 64; off <<= 1) wm = fmaxf(wm, __shfl_xor(wm, off, 64));
    if (lane == 0) wred[wid] = wm;
    __syncthreads();
    if (t == 0) {
        float M = wred[0];
#pragma unroll
        for (int j = 1; j < 16; ++j) M = fmaxf(M, wred[j]);
        sh_M = M;
    }
    __syncthreads();
    float M = sh_M;
    float zs = z * expf(m - M);
#pragma unroll
    for (int off = 1; off < 64; off <<= 1) zs += __shfl_xor(zs, off, 64);
    if (lane == 0) wred[wid] = zs;
    __syncthreads();
    if (t == 0) {
        float Z = 0.f;
#pragma unroll
        for (int j = 0; j < 16; ++j) Z += wred[j];
        sh_Z = Z;
    }
    __syncthreads();
    float invZ = 1.0f / sh_Z;

    float* pp = probs + (size_t)bh * S_;
    unsigned* kb = kbm + bh * 256;
#pragma unroll
    for (int i = 0; i < 8; ++i) {
        int s = i * 1024 + t;
        bool kp = ua[PAD(s)] > ut;
        pp[s] = kp ? expf(fp[s] - M) * invZ : 0.f;
        unsigned long long bal = __ballot(kp);
        if (lane == 0) {
            int wd = s >> 5;
            kb[wd]     = (unsigned)bal;
            kb[wd + 1] = (unsigned)(bal >> 32);
        }
    }
}

// ---------------- K3b: union keep-set per (b,kvh) -> compacted row list + probs ----------------
// pc/list overlay fsc/asc (dead after K3).
__global__ __launch_bounds__(256) void k3b_compact(
    const unsigned* __restrict__ kbm, const float* __restrict__ probs,
    int* __restrict__ counts, int* __restrict__ lst, float* __restrict__ pc)
{
    int g = blockIdx.x;           // g = b*4 + kvh ; heads = g*4 + j
    int t = threadIdx.x;          // one 32-row word per thread
    __shared__ int sc[256];

    unsigned m0 = kbm[(g * 4 + 0) * 256 + t];
    unsigned m1 = kbm[(g * 4 + 1) * 256 + t];
    unsigned m2 = kbm[(g * 4 + 2) * 256 + t];
    unsigned m3 = kbm[(g * 4 + 3) * 256 + t];
    unsigned u = m0 | m1 | m2 | m3;
    int cnt = __popc(u);
    sc[t] = cnt; __syncthreads();
    for (int off = 1; off < 256; off <<= 1) {
        int v = (t >= off) ? sc[t - off] : 0;
        __syncthreads();
        sc[t] += v;
        __syncthreads();
    }
    int base = sc[t] - cnt;
    int total = sc[255];

    const float* p0 = probs + (size_t)(g * 4) * S_;
    int* lg = lst + g * 8192;
    float* pg = pc + (size_t)g * 4 * 8192;
#pragma unroll
    for (int bit = 0; bit < 32; ++bit) {
        if ((u >> bit) & 1u) {
            int row = t * 32 + bit;
            int pos = base + __popc(u & ((1u << bit) - 1u));
            lg[pos] = row;
            pg[pos]         = ((m0 >> bit) & 1u) ? p0[row]          : 0.f;
            pg[8192 + pos]  = ((m1 >> bit) & 1u) ? p0[S_ + row]     : 0.f;
            pg[16384 + pos] = ((m2 >> bit) & 1u) ? p0[2 * S_ + row] : 0.f;
            pg[24576 + pos] = ((m3 >> bit) & 1u) ? p0[3 * S_ + row] : 0.f;
        }
    }
    int pad_end = (total + 127) & ~127;
    for (int p = total + t; p < pad_end; p += 256) {
        lg[p] = PAST_;
        pg[p] = 0.f; pg[8192 + p] = 0.f; pg[16384 + p] = 0.f; pg[24576 + p] = 0.f;
    }
    if (t == 0) counts[g] = total;
}

// ---------------- K4: weighted V over compacted row list ----------------
// grid = 16 (b,kvh) * 64 chunks of 128 list entries; wave owns 32 entries, 2/iter.
__global__ __launch_bounds__(256) void k4_wv(
    const float* __restrict__ past_value, const float* __restrict__ vnew,
    const int* __restrict__ counts, const int* __restrict__ lst,
    const float* __restrict__ pc, float* __restrict__ ypart)
{
    int bkv = blockIdx.x >> 6, chunk = blockIdx.x & 63;
    int pad_end = (counts[bkv] + 127) & ~127;
    if (chunk * 128 >= pad_end) return;     // K5 never reads these chunks
    int b = bkv >> 2, kvh = bkv & 3;
    int w = threadIdx.x >> 6, lane = threadIdx.x & 63;

    const float* vbase = past_value + (size_t)(b * KVH_ + kvh) * PAST_ * D_;
    const float* vnrow = vnew + (b * KVH_ + kvh) * D_;
    const int* lw = lst + bkv * 8192 + chunk * 128 + w * 32;
    const float* pw = pc + (size_t)bkv * 4 * 8192 + chunk * 128 + w * 32;

    float acc[4][4] = {{0.f}};

    int rA = lw[0], rB = lw[1];
    const float* prA = (rA < PAST_) ? (vbase + (size_t)rA * D_) : vnrow;
    const float* prB = (rB < PAST_) ? (vbase + (size_t)rB * D_) : vnrow;
    float4 vnA = *(const float4*)(prA + lane * 4);
    float4 vnB = *(const float4*)(prB + lane * 4);
    float2 pn0 = *(const float2*)(pw);
    float2 pn1 = *(const float2*)(pw + 8192);
    float2 pn2 = *(const float2*)(pw + 16384);
    float2 pn3 = *(const float2*)(pw + 24576);

    for (int it = 0; it < 16; ++it) {
        float4 vA = vnA, vB = vnB;
        float2 c0 = pn0, c1 = pn1, c2 = pn2, c3 = pn3;
        if (it < 15) {
            int p2 = 2 * it + 2;
            int rA2 = lw[p2], rB2 = lw[p2 + 1];
            const float* pA = (rA2 < PAST_) ? (vbase + (size_t)rA2 * D_) : vnrow;
            const float* pB = (rB2 < PAST_) ? (vbase + (size_t)rB2 * D_) : vnrow;
            vnA = *(const float4*)(pA + lane * 4);
            vnB = *(const float4*)(pB + lane * 4);
            pn0 = *(const float2*)(pw + p2);
            pn1 = *(const float2*)(pw + 8192 + p2);
            pn2 = *(const float2*)(pw + 16384 + p2);
            pn3 = *(const float2*)(pw + 24576 + p2);
        }
        acc[0][0] += c0.x * vA.x + c0.y * vB.x;
        acc[0][1] += c0.x * vA.y + c0.y * vB.y;
        acc[0][2] += c0.x * vA.z + c0.y * vB.z;
        acc[0][3] += c0.x * vA.w + c0.y * vB.w;
        acc[1][0] += c1.x * vA.x + c1.y * vB.x;
        acc[1][1] += c1.x * vA.y + c1.y * vB.y;
        acc[1][2] += c1.x * vA.z + c1.y * vB.z;
        acc[1][3] += c1.x * vA.w + c1.y * vB.w;
        acc[2][0] += c2.x * vA.x + c2.y * vB.x;
        acc[2][1] += c2.x * vA.y + c2.y * vB.y;
        acc[2][2] += c2.x * vA.z + c2.y * vB.z;
        acc[2][3] += c2.x * vA.w + c2.y * vB.w;
        acc[3][0] += c3.x * vA.x + c3.y * vB.x;
        acc[3][1] += c3.x * vA.y + c3.y * vB.y;
        acc[3][2] += c3.x * vA.z + c3.y * vB.z;
        acc[3][3] += c3.x * vA.w + c3.y * vB.w;
    }

    __shared__ float part[4][4][256];
#pragma unroll
    for (int j = 0; j < 4; ++j)
#pragma unroll
        for (int t4 = 0; t4 < 4; ++t4)
            part[w][j][lane * 4 + t4] = acc[j][t4];
    __syncthreads();

    float* yo = ypart + (size_t)(chunk * 16 + bkv) * 1024;
    for (int o = threadIdx.x; o < 1024; o += 256) {
        int j = o >> 8, d = o & 255;
        yo[o] = part[0][j][d] + part[1][j][d] + part[2][j][d] + part[3][j][d];
    }
}

// ---------------- K5: reduce partials -> y flat (only live chunks) ----------------
__global__ __launch_bounds__(256) void k5_reduce(
    const float* __restrict__ ypart, const int* __restrict__ counts, float* __restrict__ yflat)
{
    int bh = blockIdx.x; int b = bh >> 4, h = bh & 15;
    int kvh = h >> 2, j = h & 3;
    int d = threadIdx.x;
    int bkv = b * 4 + kvh;
    int pcn = (counts[bkv] + 127) >> 7;
    float sum = 0.f;
    for (int c = 0; c < pcn; ++c)
        sum += ypart[(size_t)(c * 16 + bkv) * 1024 + j * 256 + d];
    yflat[b * 4096 + h * 256 + d] = sum;
}

// ---------------- K6: output projection GEMV ----------------
__global__ __launch_bounds__(256) void k6_out(
    const float* __restrict__ Wo, const float* __restrict__ yflat, float* __restrict__ out)
{
    int i = blockIdx.x;
    const float* wrow = Wo + (size_t)i * HID_;
    float acc[4] = {0.f, 0.f, 0.f, 0.f};
#pragma unroll
    for (int ii = 0; ii < 4; ++ii) {
        int c = (threadIdx.x + 256 * ii) * 4;
        float4 wv = *(const float4*)(wrow + c);
#pragma unroll
        for (int b = 0; b < 4; ++b) {
            float4 yv = *(const float4*)(yflat + b * 4096 + c);
            acc[b] += wv.x * yv.x + wv.y * yv.y + wv.z * yv.z + wv.w * yv.w;
        }
    }
#pragma unroll
    for (int off = 1; off < 64; off <<= 1)
#pragma unroll
        for (int b = 0; b < 4; ++b) acc[b] += __shfl_xor(acc[b], off, 64);
    __shared__ float red[4][4];
    int wv_ = threadIdx.x >> 6, ln = threadIdx.x & 63;
    if (ln == 0)
#pragma unroll
        for (int b = 0; b < 4; ++b) red[wv_][b] = acc[b];
    __syncthreads();
    if (threadIdx.x < 4) {
        int b = threadIdx.x;
        out[b * HID_ + i] = red[0][b] + red[1][b] + red[2][b] + red[3][b];
    }
}

extern "C" void kernel_launch(void* const* d_in, const int* in_sizes, int n_in,
                              void* d_out, int out_size, void* d_ws, size_t ws_size,
                              hipStream_t stream)
{
    const float* hidden = (const float*)d_in[0];
    const float* amask  = (const float*)d_in[1];
    const int*   posids = (const int*)d_in[2];
    const float* pkey   = (const float*)d_in[3];
    const float* pval   = (const float*)d_in[4];
    const float* Wq     = (const float*)d_in[5];
    const float* Wk     = (const float*)d_in[6];
    const float* Wv     = (const float*)d_in[7];
    const float* Wo     = (const float*)d_in[8];
    float* out = (float*)d_out;
    float* ws  = (float*)d_ws;

    float* q_ws   = ws + OFF_Q;
    float* knew   = ws + OFF_KN;
    float* vnew   = ws + OFF_VN;
    float* scale  = ws + OFF_SCALE;
    unsigned* cmask = (unsigned*)(ws + OFF_CMASK);
    float* ropet  = ws + OFF_ROPE;
    unsigned* kbm = (unsigned*)(ws + OFF_KBM);
    int* counts   = (int*)(ws + OFF_CNT);
    float* fsc    = ws + OFF_F;
    float* asc    = ws + OFF_A;
    float* probs  = ws + OFF_P;
    float* ypart  = ws + OFF_YP;
    // aliases over dead buffers:
    float* pc     = ws + OFF_PC;    // overlays fsc
    int* lst      = (int*)(ws + OFF_LIST);  // overlays asc
    float* yflat  = ws + OFF_Y;     // overlays kbm

    k0_rope <<<dim3(1),    dim3(256), 0, stream>>>(posids, ropet);
    k1_qkv  <<<dim3(3072), dim3(256), 0, stream>>>(hidden, ropet, Wq, Wk, Wv, q_ws, knew, vnew);
    k1b_chan<<<dim3(64),   dim3(256), 0, stream>>>(q_ws, scale, cmask);
    k2_scores<<<dim3(2048), dim3(256), 0, stream>>>(pkey, knew, q_ws, scale, cmask, amask, fsc, asc);
    k3_select<<<dim3(64),  dim3(1024), 0, stream>>>(fsc, asc, probs, kbm);
    k3b_compact<<<dim3(16), dim3(256), 0, stream>>>(kbm, probs, counts, lst, pc);
    k4_wv   <<<dim3(1024), dim3(256), 0, stream>>>(pval, vnew, counts, lst, pc, ypart);
    k5_reduce<<<dim3(64),  dim3(256), 0, stream>>>(ypart, counts, yflat);
    k6_out  <<<dim3(4096), dim3(256), 0, stream>>>(Wo, yflat, out);
}

// Round 3
// 425.362 us; speedup vs baseline: 1.1162x; 1.1162x over previous
//
#include <hip/hip_runtime.h>
#include <cmath>

#define B_   4
#define H_   16
#define KVH_ 4
#define D_   256
#define HID_ 4096
#define PAST_ 8191
#define S_   8192
#define KKEEP_ 2048
#define R_   128

// workspace layout (float offsets) — total 2,662,976 floats (~10.65 MB)
#define OFF_Q     0         // 16384
#define OFF_KN    16384     // 4096
#define OFF_VN    20480     // 4096
#define OFF_SCALE 24576     // 64
#define OFF_CMASK 24640     // 512
#define OFF_F     25152     // 524288
#define OFF_A     549440    // 524288
#define OFF_P     1073728   // 524288
#define OFF_YP    1598016   // 64*16*1024 = 1048576
#define OFF_Y     2646592   // 16384

// nontemporal 16B load (single-use streams: weights, K cache, V cache)
typedef float f32x4_t __attribute__((ext_vector_type(4)));
__device__ __forceinline__ float4 ntld4(const float* p) {
    f32x4_t v = __builtin_nontemporal_load((const f32x4_t*)p);
    return make_float4(v.x, v.y, v.z, v.w);
}

// ---------------- K1: QKV GEMV (no rope — k1b applies it) ----------------
__global__ __launch_bounds__(256) void k1_qkv(
    const float* __restrict__ hidden,
    const float* __restrict__ Wq, const float* __restrict__ Wk, const float* __restrict__ Wv,
    float* __restrict__ q_ws, float* __restrict__ knew, float* __restrict__ vnew)
{
    int slot = blockIdx.x >> 7;
    int d    = blockIdx.x & 127;
    const float* W; float* outp; int head; int bstride;
    if (slot < 16)      { W = Wq; head = slot;      outp = q_ws + head * D_; bstride = H_ * D_; }
    else if (slot < 20) { W = Wk; head = slot - 16; outp = knew + head * D_; bstride = KVH_ * D_; }
    else                { W = Wv; head = slot - 20; outp = vnew + head * D_; bstride = KVH_ * D_; }

    int rowbase = head * D_ + d;
    const float* w0 = W + (size_t)rowbase * HID_;
    const float* w1 = W + (size_t)(rowbase + 128) * HID_;

    float acc0[4] = {0.f, 0.f, 0.f, 0.f};
    float acc1[4] = {0.f, 0.f, 0.f, 0.f};
#pragma unroll
    for (int i = 0; i < 4; ++i) {
        int c = (threadIdx.x + 256 * i) * 4;
        float4 a0 = ntld4(w0 + c);
        float4 a1 = ntld4(w1 + c);
#pragma unroll
        for (int b = 0; b < 4; ++b) {
            float4 hv = *(const float4*)(hidden + b * HID_ + c);
            acc0[b] += a0.x * hv.x + a0.y * hv.y + a0.z * hv.z + a0.w * hv.w;
            acc1[b] += a1.x * hv.x + a1.y * hv.y + a1.z * hv.z + a1.w * hv.w;
        }
    }
#pragma unroll
    for (int off = 1; off < 64; off <<= 1) {
#pragma unroll
        for (int b = 0; b < 4; ++b) {
            acc0[b] += __shfl_xor(acc0[b], off, 64);
            acc1[b] += __shfl_xor(acc1[b], off, 64);
        }
    }
    __shared__ float red[4][8];
    int wv = threadIdx.x >> 6, ln = threadIdx.x & 63;
    if (ln == 0) {
#pragma unroll
        for (int b = 0; b < 4; ++b) { red[wv][b] = acc0[b]; red[wv][4 + b] = acc1[b]; }
    }
    __syncthreads();
    if (threadIdx.x < 8) {
        int b = threadIdx.x >> 1, hf = (threadIdx.x & 1) * 4;
        float s = red[0][hf + b] + red[1][hf + b] + red[2][hf + b] + red[3][hf + b];
        outp[b * bstride + d + (hf ? 128 : 0)] = s;
    }
}

// ---------------- K1b: RoPE (q + knew) + top-128 channel selection per (b,h) ----------------
__global__ __launch_bounds__(256) void k1b_chan(
    float* __restrict__ q_ws, float* __restrict__ knew, const int* __restrict__ pos_ids,
    float* __restrict__ scale_ws, unsigned* __restrict__ cmask_ws)
{
    int bh = blockIdx.x;
    int t  = threadIdx.x;
    __shared__ unsigned ua[256];
    __shared__ float red[256];
    __shared__ unsigned bm[8];
    __shared__ float s_all;

    // RoPE: thread t handles channel t of q row bh (and knew row bh when bh<16).
    int d = t & 127;
    float x = (float)d * (1.0f / 128.0f);
    float invf = 1.0f / powf(10000.0f, x);

    float qme = q_ws[bh * 256 + t];
    float qot = q_ws[bh * 256 + (t ^ 128)];
    float angq = (float)pos_ids[bh >> 4] * invf;
    double aqd = (double)angq;
    float cq = (float)cos(aqd), sq = (float)sin(aqd);
    float o = qme * cq + ((t < 128) ? -qot : qot) * sq;

    float ko = 0.f;
    if (bh < 16) {
        float kme = knew[bh * 256 + t];
        float kot = knew[bh * 256 + (t ^ 128)];
        float angk = (float)pos_ids[bh >> 2] * invf;
        double akd = (double)angk;
        float ck = (float)cos(akd), sk = (float)sin(akd);
        ko = kme * ck + ((t < 128) ? -kot : kot) * sk;
    }

    float aq = fabsf(o);
    ua[t] = __float_as_uint(aq);
    if (t < 8) bm[t] = 0u;
    __syncthreads();                 // all pre-rope reads complete
    q_ws[bh * 256 + t] = o;          // write roped values back
    if (bh < 16) knew[bh * 256 + t] = ko;

    unsigned mine = ua[t];
    int rank = 0;
    for (int i = 0; i < 256; ++i) {
        unsigned o2 = ua[i];
        rank += (o2 > mine) || (o2 == mine && i < t);
    }
    bool kept = rank < R_;
    if (kept) atomicOr(&bm[t >> 5], 1u << (t & 31));

    red[t] = aq; __syncthreads();
    for (int off = 128; off; off >>= 1) { if (t < off) red[t] += red[t + off]; __syncthreads(); }
    if (t == 0) s_all = red[0];
    __syncthreads();
    red[t] = kept ? aq : 0.f; __syncthreads();
    for (int off = 128; off; off >>= 1) { if (t < off) red[t] += red[t + off]; __syncthreads(); }
    if (t == 0) scale_ws[bh] = sqrtf(256.0f * red[0] / s_all);
    if (t < 8) cmask_ws[bh * 8 + t] = bm[t];
}

// ---------------- K2: full + approx scores (2-row deep prefetch) ----------------
__global__ __launch_bounds__(256) void k2_scores(
    const float* __restrict__ past_key, const float* __restrict__ knew,
    const float* __restrict__ q_ws, const float* __restrict__ scale_ws,
    const unsigned* __restrict__ cmask_ws, const float* __restrict__ amask,
    float* __restrict__ fsc, float* __restrict__ asc)
{
    int bkv   = blockIdx.x >> 7;
    int chunk = blockIdx.x & 127;
    int b = bkv >> 2, kvh = bkv & 3;
    int w = threadIdx.x >> 6, lane = threadIdx.x & 63;
    int g = lane >> 4, m = lane & 15;
    int h = kvh * 4 + g;

    const float* qp = q_ws + (b * H_ + h) * D_;
    const unsigned* cm = cmask_ws + (b * H_ + h) * 8;
    float inv_scale = 1.0f / scale_ws[b * H_ + h];

    float qr[16], ar[16];
#pragma unroll
    for (int i = 0; i < 4; ++i)
#pragma unroll
        for (int t = 0; t < 4; ++t) {
            int c = i * 64 + m * 4 + t;
            float q = qp[c];
            qr[i * 4 + t] = q;
            ar[i * 4 + t] = ((cm[c >> 5] >> (c & 31)) & 1u) ? q : 0.f;
        }

    const float* kbase = past_key + (size_t)(b * KVH_ + kvh) * PAST_ * D_;
    const float* knrow = knew + (b * KVH_ + kvh) * D_;
    float* fout = fsc + (size_t)(b * H_ + h) * S_;
    float* aout = asc + (size_t)(b * H_ + h) * S_;
    const float* mrow = amask + b * S_;
    int s0 = chunk * 64 + w * 16;

    const float* rA = (s0     < PAST_) ? (kbase + (size_t)s0 * D_)       : knrow;
    const float* rB = (s0 + 1 < PAST_) ? (kbase + (size_t)(s0 + 1) * D_) : knrow;
    float4 nA0 = ntld4(rA + m * 4);
    float4 nA1 = ntld4(rA + 64 + m * 4);
    float4 nA2 = ntld4(rA + 128 + m * 4);
    float4 nA3 = ntld4(rA + 192 + m * 4);
    float4 nB0 = ntld4(rB + m * 4);
    float4 nB1 = ntld4(rB + 64 + m * 4);
    float4 nB2 = ntld4(rB + 128 + m * 4);
    float4 nB3 = ntld4(rB + 192 + m * 4);

    for (int it = 0; it < 8; ++it) {
        int sA = s0 + 2 * it;
        float4 cA0 = nA0, cA1 = nA1, cA2 = nA2, cA3 = nA3;
        float4 cB0 = nB0, cB1 = nB1, cB2 = nB2, cB3 = nB3;
        if (it < 7) {
            int sn = sA + 2;
            const float* pA = (sn     < PAST_) ? (kbase + (size_t)sn * D_)       : knrow;
            const float* pB = (sn + 1 < PAST_) ? (kbase + (size_t)(sn + 1) * D_) : knrow;
            nA0 = ntld4(pA + m * 4);
            nA1 = ntld4(pA + 64 + m * 4);
            nA2 = ntld4(pA + 128 + m * 4);
            nA3 = ntld4(pA + 192 + m * 4);
            nB0 = ntld4(pB + m * 4);
            nB1 = ntld4(pB + 64 + m * 4);
            nB2 = ntld4(pB + 128 + m * 4);
            nB3 = ntld4(pB + 192 + m * 4);
        }
        float fullA = 0.f, apprA = 0.f, fullB = 0.f, apprB = 0.f;
        fullA += qr[0]*cA0.x + qr[1]*cA0.y + qr[2]*cA0.z + qr[3]*cA0.w;
        apprA += ar[0]*cA0.x + ar[1]*cA0.y + ar[2]*cA0.z + ar[3]*cA0.w;
        fullA += qr[4]*cA1.x + qr[5]*cA1.y + qr[6]*cA1.z + qr[7]*cA1.w;
        apprA += ar[4]*cA1.x + ar[5]*cA1.y + ar[6]*cA1.z + ar[7]*cA1.w;
        fullA += qr[8]*cA2.x + qr[9]*cA2.y + qr[10]*cA2.z + qr[11]*cA2.w;
        apprA += ar[8]*cA2.x + ar[9]*cA2.y + ar[10]*cA2.z + ar[11]*cA2.w;
        fullA += qr[12]*cA3.x + qr[13]*cA3.y + qr[14]*cA3.z + qr[15]*cA3.w;
        apprA += ar[12]*cA3.x + ar[13]*cA3.y + ar[14]*cA3.z + ar[15]*cA3.w;
        fullB += qr[0]*cB0.x + qr[1]*cB0.y + qr[2]*cB0.z + qr[3]*cB0.w;
        apprB += ar[0]*cB0.x + ar[1]*cB0.y + ar[2]*cB0.z + ar[3]*cB0.w;
        fullB += qr[4]*cB1.x + qr[5]*cB1.y + qr[6]*cB1.z + qr[7]*cB1.w;
        apprB += ar[4]*cB1.x + ar[5]*cB1.y + ar[6]*cB1.z + ar[7]*cB1.w;
        fullB += qr[8]*cB2.x + qr[9]*cB2.y + qr[10]*cB2.z + qr[11]*cB2.w;
        apprB += ar[8]*cB2.x + ar[9]*cB2.y + ar[10]*cB2.z + ar[11]*cB2.w;
        fullB += qr[12]*cB3.x + qr[13]*cB3.y + qr[14]*cB3.z + qr[15]*cB3.w;
        apprB += ar[12]*cB3.x + ar[13]*cB3.y + ar[14]*cB3.z + ar[15]*cB3.w;
#pragma unroll
        for (int off = 1; off < 16; off <<= 1) {
            fullA += __shfl_xor(fullA, off, 64);
            apprA += __shfl_xor(apprA, off, 64);
            fullB += __shfl_xor(fullB, off, 64);
            apprB += __shfl_xor(apprB, off, 64);
        }
        float2 mv = *(const float2*)(mrow + sA);
        if (m == 0) {
            float2 o; o.x = fullA * 0.0625f + mv.x; o.y = fullB * 0.0625f + mv.y;
            *(float2*)(fout + sA) = o;
        } else if (m == 1) {
            float2 o; o.x = apprA * inv_scale + mv.x; o.y = apprB * inv_scale + mv.y;
            *(float2*)(aout + sA) = o;
        }
    }
}

// ---------------- K3: radix-select top-2048 + softmax -> probs ----------------
#define PAD(s) ((s) + ((s) >> 5))
__global__ __launch_bounds__(1024) void k3_select(
    const float* __restrict__ fsc, const float* __restrict__ asc, float* __restrict__ probs)
{
    int bh = blockIdx.x;
    int t  = threadIdx.x;
    int lane = t & 63, wid = t >> 6;
    __shared__ unsigned ua[8448];
    __shared__ unsigned hist2[16 * 257];
    __shared__ unsigned hist[256];
    __shared__ unsigned sf[256];
    __shared__ int wsum[16], wbase[16];
    __shared__ float wred[16];
    __shared__ unsigned sh_bin; __shared__ int sh_rem;
    __shared__ float sh_M, sh_Z;

    const float* ap = asc + (size_t)bh * S_;
    const float* fp = fsc + (size_t)bh * S_;

#pragma unroll
    for (int i = 0; i < 8; ++i) {
        int s = i * 1024 + t;
        unsigned u = __float_as_uint(ap[s]);
        u ^= (u & 0x80000000u) ? 0xFFFFFFFFu : 0x80000000u;
        ua[PAD(s)] = u;
    }

    unsigned prefix = 0; int rem = KKEEP_;
    for (int pass = 0; pass < 4; ++pass) {
        const int shift = 24 - 8 * pass;
        for (int j = t; j < 16 * 257; j += 1024) hist2[j] = 0;
        __syncthreads();
#pragma unroll
        for (int i = 0; i < 8; ++i) {
            unsigned u = ua[PAD(i * 1024 + t)];
            bool match = (pass == 0) || ((u >> (shift + 8)) == prefix);
            if (match) atomicAdd(&hist2[wid * 257 + ((u >> shift) & 255u)], 1u);
        }
        __syncthreads();
        if (t < 256) {
            unsigned hsum = 0;
#pragma unroll
            for (int w2 = 0; w2 < 16; ++w2) hsum += hist2[w2 * 257 + t];
            hist[t] = hsum;
        }
        __syncthreads();
        if (t < 64) {
            unsigned h0 = hist[t*4], h1 = hist[t*4+1], h2 = hist[t*4+2], h3 = hist[t*4+3];
            unsigned loc = h0 + h1 + h2 + h3;
            unsigned run = loc;
#pragma unroll
            for (int off = 1; off < 64; off <<= 1) {
                unsigned v = __shfl_down(run, off, 64);
                if (t + off < 64) run += v;
            }
            unsigned tail = run - loc;
            sf[t*4+3] = tail + h3;
            sf[t*4+2] = tail + h3 + h2;
            sf[t*4+1] = tail + h3 + h2 + h1;
            sf[t*4+0] = tail + loc;
        }
        __syncthreads();
        if (t < 256) {
            unsigned above = (t == 255) ? 0u : sf[t + 1];
            if (sf[t] >= (unsigned)rem && above < (unsigned)rem) {
                sh_bin = (unsigned)t;
                sh_rem = rem - (int)above;
            }
        }
        __syncthreads();
        prefix = (prefix << 8) | sh_bin;
        rem = sh_rem;
        __syncthreads();
    }
    unsigned ut = prefix; int Need = rem;

    int cnt = 0;
#pragma unroll
    for (int i = 0; i < 8; ++i)
        cnt += (ua[PAD(t * 8 + i)] == ut) ? 1 : 0;
    int inc = cnt;
#pragma unroll
    for (int off = 1; off < 64; off <<= 1) {
        int v = __shfl_up(inc, off, 64);
        if (lane >= off) inc += v;
    }
    if (lane == 63) wsum[wid] = inc;
    __syncthreads();
    if (t == 0) {
        int run = 0;
#pragma unroll
        for (int j = 0; j < 16; ++j) { int c = wsum[j]; wbase[j] = run; run += c; }
    }
    __syncthreads();
    int eqb = wbase[wid] + inc - cnt;
#pragma unroll
    for (int i = 0; i < 8; ++i) {
        int s = t * 8 + i;
        if (ua[PAD(s)] == ut) {
            ua[PAD(s)] = (eqb < Need) ? 0xFFFFFFFFu : 0u;
            ++eqb;
        }
    }
    __syncthreads();

    float m = -3.4e38f, z = 0.f;
#pragma unroll
    for (int i = 0; i < 8; ++i) {
        int s = i * 1024 + t;
        if (ua[PAD(s)] > ut) {
            float f = fp[s];
            if (f > m) { z = z * expf(m - f) + 1.f; m = f; }
            else       { z += expf(f - m); }
        }
    }
    float wm = m;
#pragma unroll
    for (int off = 1; off < 64; off <<= 1) wm = fmaxf(wm, __shfl_xor(wm, off, 64));
    if (lane == 0) wred[wid] = wm;
    __syncthreads();
    if (t == 0) {
        float M = wred[0];
#pragma unroll
        for (int j = 1; j < 16; ++j) M = fmaxf(M, wred[j]);
        sh_M = M;
    }
    __syncthreads();
    float M = sh_M;
    float zs = z * expf(m - M);
#pragma unroll
    for (int off = 1; off < 64; off <<= 1) zs += __shfl_xor(zs, off, 64);
    if (lane == 0) wred[wid] = zs;
    __syncthreads();
    if (t == 0) {
        float Z = 0.f;
#pragma unroll
        for (int j = 0; j < 16; ++j) Z += wred[j];
        sh_Z = Z;
    }
    __syncthreads();
    float invZ = 1.0f / sh_Z;

    float* pp = probs + (size_t)bh * S_;
#pragma unroll
    for (int i = 0; i < 8; ++i) {
        int s = i * 1024 + t;
        pp[s] = (ua[PAD(s)] > ut) ? expf(fp[s] - M) * invZ : 0.f;
    }
}

// ---------------- K4: weighted V partial sums (dense, 2-row deep prefetch) ----------------
__global__ __launch_bounds__(256) void k4_wv(
    const float* __restrict__ past_value, const float* __restrict__ vnew,
    const float* __restrict__ probs, float* __restrict__ ypart)
{
    int bkv = blockIdx.x >> 6, chunk = blockIdx.x & 63;
    int b = bkv >> 2, kvh = bkv & 3;
    int w = threadIdx.x >> 6, lane = threadIdx.x & 63;
    int h0 = kvh * 4;

    const float* p0 = probs + (size_t)(b * H_ + h0) * S_;
    const float* vbase = past_value + (size_t)(b * KVH_ + kvh) * PAST_ * D_;
    const float* vnrow = vnew + (b * KVH_ + kvh) * D_;

    float acc[4][4] = {{0.f}};
    int s0 = chunk * 128 + w * 32;

    const float* rA = (s0     < PAST_) ? (vbase + (size_t)s0 * D_)       : vnrow;
    const float* rB = (s0 + 1 < PAST_) ? (vbase + (size_t)(s0 + 1) * D_) : vnrow;
    float4 vnA = ntld4(rA + lane * 4);
    float4 vnB = ntld4(rB + lane * 4);
    float2 pn0 = *(const float2*)(p0 + s0);
    float2 pn1 = *(const float2*)(p0 + S_ + s0);
    float2 pn2 = *(const float2*)(p0 + 2 * S_ + s0);
    float2 pn3 = *(const float2*)(p0 + 3 * S_ + s0);

    for (int it = 0; it < 16; ++it) {
        float4 vA = vnA, vB = vnB;
        float2 c0 = pn0, c1 = pn1, c2 = pn2, c3 = pn3;
        if (it < 15) {
            int sn = s0 + 2 * it + 2;
            const float* pA = (sn     < PAST_) ? (vbase + (size_t)sn * D_)       : vnrow;
            const float* pB = (sn + 1 < PAST_) ? (vbase + (size_t)(sn + 1) * D_) : vnrow;
            vnA = ntld4(pA + lane * 4);
            vnB = ntld4(pB + lane * 4);
            pn0 = *(const float2*)(p0 + sn);
            pn1 = *(const float2*)(p0 + S_ + sn);
            pn2 = *(const float2*)(p0 + 2 * S_ + sn);
            pn3 = *(const float2*)(p0 + 3 * S_ + sn);
        }
        acc[0][0] += c0.x * vA.x + c0.y * vB.x;
        acc[0][1] += c0.x * vA.y + c0.y * vB.y;
        acc[0][2] += c0.x * vA.z + c0.y * vB.z;
        acc[0][3] += c0.x * vA.w + c0.y * vB.w;
        acc[1][0] += c1.x * vA.x + c1.y * vB.x;
        acc[1][1] += c1.x * vA.y + c1.y * vB.y;
        acc[1][2] += c1.x * vA.z + c1.y * vB.z;
        acc[1][3] += c1.x * vA.w + c1.y * vB.w;
        acc[2][0] += c2.x * vA.x + c2.y * vB.x;
        acc[2][1] += c2.x * vA.y + c2.y * vB.y;
        acc[2][2] += c2.x * vA.z + c2.y * vB.z;
        acc[2][3] += c2.x * vA.w + c2.y * vB.w;
        acc[3][0] += c3.x * vA.x + c3.y * vB.x;
        acc[3][1] += c3.x * vA.y + c3.y * vB.y;
        acc[3][2] += c3.x * vA.z + c3.y * vB.z;
        acc[3][3] += c3.x * vA.w + c3.y * vB.w;
    }

    __shared__ float part[4][4][256];
#pragma unroll
    for (int j = 0; j < 4; ++j)
#pragma unroll
        for (int t4 = 0; t4 < 4; ++t4)
            part[w][j][lane * 4 + t4] = acc[j][t4];
    __syncthreads();

    float* yo = ypart + (size_t)(chunk * 16 + bkv) * 1024;
    for (int o = threadIdx.x; o < 1024; o += 256) {
        int j = o >> 8, d = o & 255;
        yo[o] = part[0][j][d] + part[1][j][d] + part[2][j][d] + part[3][j][d];
    }
}

// ---------------- K5: reduce partials -> y flat ----------------
__global__ __launch_bounds__(256) void k5_reduce(const float* __restrict__ ypart, float* __restrict__ yflat)
{
    int bh = blockIdx.x; int b = bh >> 4, h = bh & 15;
    int kvh = h >> 2, j = h & 3;
    int d = threadIdx.x;
    int bkv = b * 4 + kvh;
    float sum = 0.f;
    for (int c = 0; c < 64; ++c)
        sum += ypart[(size_t)(c * 16 + bkv) * 1024 + j * 256 + d];
    yflat[b * 4096 + h * 256 + d] = sum;
}

// ---------------- K6: output projection GEMV ----------------
__global__ __launch_bounds__(256) void k6_out(
    const float* __restrict__ Wo, const float* __restrict__ yflat, float* __restrict__ out)
{
    int i = blockIdx.x;
    const float* wrow = Wo + (size_t)i * HID_;
    float acc[4] = {0.f, 0.f, 0.f, 0.f};
#pragma unroll
    for (int ii = 0; ii < 4; ++ii) {
        int c = (threadIdx.x + 256 * ii) * 4;
        float4 wv = ntld4(wrow + c);
#pragma unroll
        for (int b = 0; b < 4; ++b) {
            float4 yv = *(const float4*)(yflat + b * 4096 + c);
            acc[b] += wv.x * yv.x + wv.y * yv.y + wv.z * yv.z + wv.w * yv.w;
        }
    }
#pragma unroll
    for (int off = 1; off < 64; off <<= 1)
#pragma unroll
        for (int b = 0; b < 4; ++b) acc[b] += __shfl_xor(acc[b], off, 64);
    __shared__ float red[4][4];
    int wv_ = threadIdx.x >> 6, ln = threadIdx.x & 63;
    if (ln == 0)
#pragma unroll
        for (int b = 0; b < 4; ++b) red[wv_][b] = acc[b];
    __syncthreads();
    if (threadIdx.x < 4) {
        int b = threadIdx.x;
        out[b * HID_ + i] = red[0][b] + red[1][b] + red[2][b] + red[3][b];
    }
}

extern "C" void kernel_launch(void* const* d_in, const int* in_sizes, int n_in,
                              void* d_out, int out_size, void* d_ws, size_t ws_size,
                              hipStream_t stream)
{
    const float* hidden = (const float*)d_in[0];
    const float* amask  = (const float*)d_in[1];
    const int*   posids = (const int*)d_in[2];
    const float* pkey   = (const float*)d_in[3];
    const float* pval   = (const float*)d_in[4];
    const float* Wq     = (const float*)d_in[5];
    const float* Wk     = (const float*)d_in[6];
    const float* Wv     = (const float*)d_in[7];
    const float* Wo     = (const float*)d_in[8];
    float* out = (float*)d_out;
    float* ws  = (float*)d_ws;

    float* q_ws   = ws + OFF_Q;
    float* knew   = ws + OFF_KN;
    float* vnew   = ws + OFF_VN;
    float* scale  = ws + OFF_SCALE;
    unsigned* cmask = (unsigned*)(ws + OFF_CMASK);
    float* fsc    = ws + OFF_F;
    float* asc    = ws + OFF_A;
    float* probs  = ws + OFF_P;
    float* ypart  = ws + OFF_YP;
    float* yflat  = ws + OFF_Y;

    k1_qkv  <<<dim3(3072), dim3(256), 0, stream>>>(hidden, Wq, Wk, Wv, q_ws, knew, vnew);
    k1b_chan<<<dim3(64),   dim3(256), 0, stream>>>(q_ws, knew, posids, scale, cmask);
    k2_scores<<<dim3(2048), dim3(256), 0, stream>>>(pkey, knew, q_ws, scale, cmask, amask, fsc, asc);
    k3_select<<<dim3(64),  dim3(1024), 0, stream>>>(fsc, asc, probs);
    k4_wv   <<<dim3(1024), dim3(256), 0, stream>>>(pval, vnew, probs, ypart);
    k5_reduce<<<dim3(64),  dim3(256), 0, stream>>>(ypart, yflat);
    k6_out  <<<dim3(4096), dim3(256), 0, stream>>>(Wo, yflat, out);
}